// Round 16
// baseline (76.129 us; speedup 1.0000x reference)
//
#include <hip/hip_runtime.h>

// Product quantizer: N=16384, D=1024, M=64 subspaces, K=256 codes, d=16.
// Three phases (all on `stream`, sequential):
//  1. pq_main: split-bf16 16x16x32 MFMA scores s = x·c - 0.5||c||^2 (argmax ==
//     argmin dist). A = [ch|cl] codebook frags (lane-permuted LDS, 0 conflicts,
//     R9-verified), B1=[xh|xh], B2=[xl|xl] -> full (ch+cl)(xh+xl). Emits a 1-BYTE
//     code per (n,m) into the first 64 bytes of out row n. Masked top-2 gap <
//     MARGIN -> LDS-batched flags.
//  2. pq_refine: exact f64 re-decision for flagged (n,m), first-min tie-break.
//  3. pq_gather: reads code bytes, writes full 4KB rows coalesced (R4-verified).
// R16: R15 (unroll-2 window control -> VGPR=32, no spill, 54.5us main @ 53% occ)
// + __launch_bounds__(256,8). Compiler already allocates exactly 32 regs =
// 256/8 budget, so the tighter hint cannot force spill; it only raises the
// promised/granted residency (theoretical: 8 blocks/CU, LDS 18.4KB*8 <= 160KB).
// Tripwires: VGPR must stay 32, WRITE ~1.1MB, FETCH ~37MB; else revert to (256,4).
// NOTE: hint->VGPR budget measured: (256,6)->40, (256,4)->64, (256,8)->32;
// never set the budget below the loop's natural live need (R6/R11/R13 spills).

#define DIMS   1024
#define MSUB   64
#define KCODE  256
#define DSUB   16
#define FLCAP  128

static constexpr float MARGIN = 2e-3f;

typedef __attribute__((ext_vector_type(8))) short s16x8;
typedef __attribute__((ext_vector_type(4))) float f32x4;
typedef __attribute__((ext_vector_type(4))) unsigned int u32x4;

static __device__ __forceinline__ f32x4 mfma32(s16x8 a, s16x8 b, f32x4 c) {
    return __builtin_amdgcn_mfma_f32_16x16x32_bf16(a, b, c, 0, 0, 0);
}

// Truncation split of 4 floats into duplicated bf16 frags [xh|xh], [xl|xl].
static __device__ __forceinline__ void mk_bfrags(float4 xv, s16x8& B1, s16x8& B2) {
    unsigned u0 = __float_as_uint(xv.x), u1 = __float_as_uint(xv.y);
    unsigned u2 = __float_as_uint(xv.z), u3 = __float_as_uint(xv.w);
    unsigned h01 = (u1 & 0xFFFF0000u) | (u0 >> 16);
    unsigned h23 = (u3 & 0xFFFF0000u) | (u2 >> 16);
    float l0 = xv.x - __uint_as_float(u0 & 0xFFFF0000u);
    float l1 = xv.y - __uint_as_float(u1 & 0xFFFF0000u);
    float l2 = xv.z - __uint_as_float(u2 & 0xFFFF0000u);
    float l3 = xv.w - __uint_as_float(u3 & 0xFFFF0000u);
    unsigned l01 = (__float_as_uint(l1) & 0xFFFF0000u) | (__float_as_uint(l0) >> 16);
    unsigned l23 = (__float_as_uint(l3) & 0xFFFF0000u) | (__float_as_uint(l2) >> 16);
    B1 = __builtin_bit_cast(s16x8, (u32x4){h01, h23, h01, h23});
    B2 = __builtin_bit_cast(s16x8, (u32x4){l01, l23, l01, l23});
}

// Block = 256 threads = 4 waves, one m per block, 512 rows/block (wave: 128 rows =
// 4 passes of 32 rows = 2 sub-tiles). Grid 2048 = 64 m x 32 row-groups, XCD-grouped.
__global__ __launch_bounds__(256, 8) void pq_main(
    const float* __restrict__ embeds,
    const float* __restrict__ codebooks,
    unsigned char* __restrict__ outb,     // out viewed as bytes: code at row*4096 + m
    unsigned* __restrict__ flag_cnt,
    unsigned* __restrict__ flag_list,
    unsigned flag_cap)
{
    __shared__ u32x4 chcl[16 * 64];       // 16KB: A-frags, position kt*64 + lane
    __shared__ float cnorm[KCODE];        // 1KB: -0.5*||c||^2, code-major
    __shared__ unsigned fl_buf[FLCAP];
    __shared__ unsigned fl_cnt, fl_base;

    const int tid = threadIdx.x;
    const int bid = blockIdx.x;
    const int m   = (bid >> 3) & 63;                  // subspace
    const int g   = (bid & 7) | ((bid >> 9) << 3);    // row-group (0..31), XCD-grouped
    const float* cbm = codebooks + (size_t)m * (KCODE * DSUB);

    if (tid == 0) fl_cnt = 0;

    // ---- Stage codebook[m], chunked (low reg pressure): thread tid owns code tid.
    // Lane-permuted store: code kt*16+c, dims d*4.. -> position kt*64 + d*16 + c,
    // so reader lane l (col=l&15, ds=l>>4) finds its frag at kt*64 + l.
    {
        const float4* src = (const float4*)(cbm + tid * DSUB);
        float ss = 0.f;
        #pragma unroll
        for (int d = 0; d < 4; ++d) {
            const float4 v = src[d];
            unsigned uc0 = __float_as_uint(v.x), uc1 = __float_as_uint(v.y);
            unsigned uc2 = __float_as_uint(v.z), uc3 = __float_as_uint(v.w);
            unsigned hc01 = (uc1 & 0xFFFF0000u) | (uc0 >> 16);
            unsigned hc23 = (uc3 & 0xFFFF0000u) | (uc2 >> 16);
            float lc0 = v.x - __uint_as_float(uc0 & 0xFFFF0000u);
            float lc1 = v.y - __uint_as_float(uc1 & 0xFFFF0000u);
            float lc2 = v.z - __uint_as_float(uc2 & 0xFFFF0000u);
            float lc3 = v.w - __uint_as_float(uc3 & 0xFFFF0000u);
            unsigned lc01 = (__float_as_uint(lc1) & 0xFFFF0000u) | (__float_as_uint(lc0) >> 16);
            unsigned lc23 = (__float_as_uint(lc3) & 0xFFFF0000u) | (__float_as_uint(lc2) >> 16);
            chcl[(tid >> 4) * 64 + d * 16 + (tid & 15)] = (u32x4){hc01, hc23, lc01, lc23};
            ss = fmaf(v.x, v.x, fmaf(v.y, v.y, fmaf(v.z, v.z, fmaf(v.w, v.w, ss))));
        }
        cnorm[tid] = -0.5f * ss;
    }
    __syncthreads();

    const int w   = tid >> 6;
    const int l   = tid & 63;
    const int col = l & 15;       // x-row within 16-row sub-tile (MFMA B/C col)
    const int ds  = l >> 4;       // k-segment / C row-group (codes)
    const int n0  = (g << 9) + (w << 7);   // 128 rows per wave

    const float* xp = embeds + (size_t)(n0 + col) * DIMS + m * DSUB + ds * 4;
    const u32x4* av  = chcl + l;                       // + kt*64 per k-tile
    const f32x4* hvp = (const f32x4*)cnorm + ds;       // + kt*4 per k-tile
    const unsigned MSK = 0xFFFFFF00u;
    const size_t RS = 16 * DIMS;                       // 16-row stride

    #pragma unroll 1
    for (int p = 0; p < 4; ++p) {
        const float4 xva = *(const float4*)(xp + (size_t)(2 * p) * RS);
        const float4 xvb = *(const float4*)(xp + (size_t)(2 * p + 1) * RS);
        s16x8 B1a, B2a, B1b, B2b;
        mk_bfrags(xva, B1a, B2a);
        mk_bfrags(xvb, B1b, B2b);

        float b0 = -3e38f, s0 = -3e38f, b1 = -3e38f, s1 = -3e38f;

        #pragma unroll 2
        for (int kt = 0; kt < 16; ++kt) {
            s16x8 A = __builtin_bit_cast(s16x8, av[kt * 64]);  // consecutive b128
            f32x4 h = hvp[kt * 4];                             // broadcast b128
            f32x4 a0 = mfma32(A, B1a, h); a0 = mfma32(A, B2a, a0);
            f32x4 a1 = mfma32(A, B1b, h); a1 = mfma32(A, B2b, a1);

            // Pack code into low-8 mantissa bits; exact top-2 via med3:
            //   s = max(s, med3(q0,q1,b)); b = max(b, max(q0,q1)).
            {
                float q0 = __uint_as_float((__float_as_uint(a0[0]) & MSK) | (unsigned)(kt * 16 + 0));
                float q1 = __uint_as_float((__float_as_uint(a0[1]) & MSK) | (unsigned)(kt * 16 + 1));
                s0 = fmaxf(s0, __builtin_amdgcn_fmed3f(q0, q1, b0));
                b0 = fmaxf(b0, fmaxf(q0, q1));
                float q2 = __uint_as_float((__float_as_uint(a0[2]) & MSK) | (unsigned)(kt * 16 + 2));
                float q3 = __uint_as_float((__float_as_uint(a0[3]) & MSK) | (unsigned)(kt * 16 + 3));
                s0 = fmaxf(s0, __builtin_amdgcn_fmed3f(q2, q3, b0));
                b0 = fmaxf(b0, fmaxf(q2, q3));
            }
            {
                float q0 = __uint_as_float((__float_as_uint(a1[0]) & MSK) | (unsigned)(kt * 16 + 0));
                float q1 = __uint_as_float((__float_as_uint(a1[1]) & MSK) | (unsigned)(kt * 16 + 1));
                s1 = fmaxf(s1, __builtin_amdgcn_fmed3f(q0, q1, b1));
                b1 = fmaxf(b1, fmaxf(q0, q1));
                float q2 = __uint_as_float((__float_as_uint(a1[2]) & MSK) | (unsigned)(kt * 16 + 2));
                float q3 = __uint_as_float((__float_as_uint(a1[3]) & MSK) | (unsigned)(kt * 16 + 3));
                s1 = fmaxf(s1, __builtin_amdgcn_fmed3f(q2, q3, b1));
                b1 = fmaxf(b1, fmaxf(q2, q3));
            }
        }

        // Fold the lane-constant ds*4 into the packed code (low byte <= 243+12).
        const unsigned d4 = (unsigned)(ds * 4);
        b0 = __uint_as_float(__float_as_uint(b0) + d4);
        s0 = __uint_as_float(__float_as_uint(s0) + d4);
        b1 = __uint_as_float(__float_as_uint(b1) + d4);
        s1 = __uint_as_float(__float_as_uint(s1) + d4);

        // Combine the 4 code-partitions (xor 16, 32): all lanes agree on both chains.
        #pragma unroll
        for (int msk = 16; msk <= 32; msk <<= 1) {
            float o;
            o = __shfl_xor(b0, msk); float q0 = __shfl_xor(s0, msk);
            s0 = fmaxf(fmaxf(s0, q0), fminf(b0, o)); b0 = fmaxf(b0, o);
            o = __shfl_xor(b1, msk); float q1 = __shfl_xor(s1, msk);
            s1 = fmaxf(fmaxf(s1, q1), fminf(b1, o)); b1 = fmaxf(b1, o);
        }

        // Lane l (l<32) owns row n0+p*32+l: chain0 = rows 0..15, chain1 = 16..31.
        if (l < 32) {
            float bs_ = (l & 16) ? b1 : b0;
            float ss_ = (l & 16) ? s1 : s0;
            const int row = n0 + p * 32 + l;
            outb[(size_t)row * (DIMS * 4) + m] =
                (unsigned char)(__float_as_uint(bs_) & 255u);

            float gap = __uint_as_float(__float_as_uint(bs_) & MSK) -
                        __uint_as_float(__float_as_uint(ss_) & MSK);
            if (gap < MARGIN) {
                unsigned ent = (unsigned)(row * 64 + m);
                unsigned q = atomicAdd(&fl_cnt, 1u);
                if (q < FLCAP) fl_buf[q] = ent;
                else { unsigned qq = atomicAdd(flag_cnt, 1u);
                       if (qq < flag_cap) flag_list[qq] = ent; }
            }
        }
    }

    // ---- One global atomic per block; coalesced flag flush ----
    __syncthreads();
    unsigned c = fl_cnt; if (c > FLCAP) c = FLCAP;
    if (tid == 0) fl_base = atomicAdd(flag_cnt, c);
    __syncthreads();
    const unsigned base = fl_base;
    for (unsigned i = tid; i < c; i += 256) {
        unsigned q = base + i;
        if (q < flag_cap) flag_list[q] = fl_buf[i];
    }
}

// One wave per flagged (n,m): exact f64 distances, first-min tie-break; fix the byte.
__global__ __launch_bounds__(256) void pq_refine(
    const float* __restrict__ embeds,
    const float* __restrict__ codebooks,
    unsigned char* __restrict__ outb,
    const unsigned* __restrict__ flag_cnt,
    const unsigned* __restrict__ flag_list,
    unsigned flag_cap)
{
    unsigned cnt = *flag_cnt;
    if (cnt > flag_cap) cnt = flag_cap;
    const int l = threadIdx.x & 63;
    const unsigned wid = (blockIdx.x << 2) | (unsigned)(threadIdx.x >> 6);
    const unsigned nw  = gridDim.x << 2;

    for (unsigned i = wid; i < cnt; i += nw) {
        const unsigned e = flag_list[i];
        const int n = (int)(e >> 6), m = (int)(e & 63u);
        const float* xrow = embeds + (size_t)n * DIMS + m * DSUB;
        double xd[DSUB];
        #pragma unroll
        for (int dd = 0; dd < DSUB; ++dd) xd[dd] = (double)xrow[dd];
        const float* cbm = codebooks + (size_t)m * (KCODE * DSUB);

        double bd = 1e300;
        int bi = 0;
        #pragma unroll 1
        for (int cc = 0; cc < 4; ++cc) {
            const int c = l * 4 + cc;                 // lane-local ascending
            const float* cp = cbm + c * DSUB;
            double s = 0.0;
            #pragma unroll
            for (int dd = 0; dd < DSUB; ++dd) {
                double diff = xd[dd] - (double)cp[dd];
                s = fma(diff, diff, s);
            }
            if (s < bd) { bd = s; bi = c; }
        }
        #pragma unroll
        for (int msk = 1; msk <= 32; msk <<= 1) {
            double ob = __shfl_xor(bd, msk);
            int   oi  = __shfl_xor(bi, msk);
            if (ob < bd || (ob == bd && oi < bi)) { bd = ob; bi = oi; }
        }
        if (l == 0) outb[(size_t)n * (DIMS * 4) + m] = (unsigned char)bi;
    }
}

// Phase 3: code bytes -> full output rows, perfectly coalesced 4KB stores.
// Thread tid: subspace m = tid>>2, segment seg = tid&3. 8 rows per block.
// Each block reads only bytes of rows it overwrites itself (sync inside).
__global__ __launch_bounds__(256) void pq_gather(
    const float* __restrict__ codebooks,
    float* __restrict__ out)
{
    const unsigned char* outb = (const unsigned char*)out;
    const int tid = threadIdx.x;
    const int m   = tid >> 2;
    const int seg = tid & 3;
    const int n0  = blockIdx.x * 8;

    unsigned char ids[8];
    #pragma unroll
    for (int r = 0; r < 8; ++r)
        ids[r] = outb[(size_t)(n0 + r) * (DIMS * 4) + m];
    __syncthreads();   // all idx reads done before any thread overwrites row bytes

    #pragma unroll
    for (int r = 0; r < 8; ++r) {
        const float4 v = *(const float4*)(codebooks +
                          ((size_t)m * KCODE + ids[r]) * DSUB + seg * 4);
        *(float4*)(out + (size_t)(n0 + r) * DIMS + tid * 4) = v;
    }
}

extern "C" void kernel_launch(void* const* d_in, const int* in_sizes, int n_in,
                              void* d_out, int out_size, void* d_ws, size_t ws_size,
                              hipStream_t stream)
{
    const float* embeds    = (const float*)d_in[0];
    const float* codebooks = (const float*)d_in[1];
    float* out = (float*)d_out;

    unsigned* flag_cnt  = (unsigned*)d_ws;
    unsigned* flag_list = (unsigned*)d_ws + 4;   // 16B offset
    unsigned flag_cap = 0;
    if (ws_size >= 32) {
        size_t cap = (ws_size - 16) / sizeof(unsigned);
        flag_cap = (cap > 0x7FFFFFFFull) ? 0x7FFFFFFFu : (unsigned)cap;
    }

    hipMemsetAsync(d_ws, 0, 16, stream);

    pq_main<<<dim3(2048), dim3(256), 0, stream>>>(
        embeds, codebooks, (unsigned char*)d_out, flag_cnt, flag_list, flag_cap);

    pq_refine<<<dim3(256), dim3(256), 0, stream>>>(
        embeds, codebooks, (unsigned char*)d_out, flag_cnt, flag_list, flag_cap);

    pq_gather<<<dim3(2048), dim3(256), 0, stream>>>(codebooks, out);
}

// Round 17
// 75.143 us; speedup vs baseline: 1.0131x; 1.0131x over previous
//
#include <hip/hip_runtime.h>

// Product quantizer: N=16384, D=1024, M=64 subspaces, K=256 codes, d=16.
// Three phases (all on `stream`, sequential):
//  1. pq_main: split-bf16 16x16x32 MFMA scores s = x·c - 0.5||c||^2 (argmax ==
//     argmin dist). A = [ch|cl] codebook frags (lane-permuted LDS, 0 conflicts,
//     R9-verified), B1=[xh|xh], B2=[xl|xl] -> full (ch+cl)(xh+xl). Emits a 1-BYTE
//     code per (n,m) into the first 64 bytes of out row n. Masked top-2 gap <
//     MARGIN -> LDS-batched flags.
//  2. pq_refine: exact f64 re-decision for flagged (n,m), first-min tie-break.
//  3. pq_gather: reads code bytes, writes full 4KB rows coalesced (R4-verified).
// R17: R15/R16 pinned at ~4 BLOCKS/CU (52% occ) regardless of launch_bounds
// promise, with statics allowing 8. Theory: per-CU workgroup-slot cap, not a
// per-wave resource. Test: 512-thread blocks (8 waves, one m, 1024 rows) keep
// the identical per-wave pipeline; if blocks/CU stays ~4, waves/CU doubles to 32.
// Tripwires: VGPR must stay 32, WRITE ~1.1MB, FETCH ~37MB; else spill -> revert.
// NOTE: hint->VGPR budget ~ (256 regs/SIMD)/(waves promised): (256,6)->40,
// (256,4)->64, (256,8)->32. Never budget below the loop's natural live need.

#define DIMS   1024
#define MSUB   64
#define KCODE  256
#define DSUB   16
#define FLCAP  256

static constexpr float MARGIN = 2e-3f;

typedef __attribute__((ext_vector_type(8))) short s16x8;
typedef __attribute__((ext_vector_type(4))) float f32x4;
typedef __attribute__((ext_vector_type(4))) unsigned int u32x4;

static __device__ __forceinline__ f32x4 mfma32(s16x8 a, s16x8 b, f32x4 c) {
    return __builtin_amdgcn_mfma_f32_16x16x32_bf16(a, b, c, 0, 0, 0);
}

// Truncation split of 4 floats into duplicated bf16 frags [xh|xh], [xl|xl].
static __device__ __forceinline__ void mk_bfrags(float4 xv, s16x8& B1, s16x8& B2) {
    unsigned u0 = __float_as_uint(xv.x), u1 = __float_as_uint(xv.y);
    unsigned u2 = __float_as_uint(xv.z), u3 = __float_as_uint(xv.w);
    unsigned h01 = (u1 & 0xFFFF0000u) | (u0 >> 16);
    unsigned h23 = (u3 & 0xFFFF0000u) | (u2 >> 16);
    float l0 = xv.x - __uint_as_float(u0 & 0xFFFF0000u);
    float l1 = xv.y - __uint_as_float(u1 & 0xFFFF0000u);
    float l2 = xv.z - __uint_as_float(u2 & 0xFFFF0000u);
    float l3 = xv.w - __uint_as_float(u3 & 0xFFFF0000u);
    unsigned l01 = (__float_as_uint(l1) & 0xFFFF0000u) | (__float_as_uint(l0) >> 16);
    unsigned l23 = (__float_as_uint(l3) & 0xFFFF0000u) | (__float_as_uint(l2) >> 16);
    B1 = __builtin_bit_cast(s16x8, (u32x4){h01, h23, h01, h23});
    B2 = __builtin_bit_cast(s16x8, (u32x4){l01, l23, l01, l23});
}

// Block = 512 threads = 8 waves, one m per block, 1024 rows/block (each wave:
// 128 rows = 4 passes of 32 rows). Grid 1024 = 64 m x 16 row-groups, XCD-grouped.
__global__ __launch_bounds__(512, 4) void pq_main(
    const float* __restrict__ embeds,
    const float* __restrict__ codebooks,
    unsigned char* __restrict__ outb,     // out viewed as bytes: code at row*4096 + m
    unsigned* __restrict__ flag_cnt,
    unsigned* __restrict__ flag_list,
    unsigned flag_cap)
{
    __shared__ u32x4 chcl[16 * 64];       // 16KB: A-frags, position kt*64 + lane
    __shared__ float cnorm[KCODE];        // 1KB: -0.5*||c||^2, code-major
    __shared__ unsigned fl_buf[FLCAP];
    __shared__ unsigned fl_cnt, fl_base;

    const int tid = threadIdx.x;
    const int bid = blockIdx.x;
    const int m   = (bid >> 3) & 63;                  // subspace
    const int g   = (bid & 7) | ((bid >> 9) << 3);    // row-group (0..15), XCD-grouped
    const float* cbm = codebooks + (size_t)m * (KCODE * DSUB);

    if (tid == 0) fl_cnt = 0;

    // ---- Stage codebook[m] by the first 256 threads: thread tid owns code tid.
    // Lane-permuted store: code kt*16+c, dims d*4.. -> position kt*64 + d*16 + c,
    // so reader lane l (col=l&15, ds=l>>4) finds its frag at kt*64 + l.
    if (tid < 256) {
        const float4* src = (const float4*)(cbm + tid * DSUB);
        float ss = 0.f;
        #pragma unroll
        for (int d = 0; d < 4; ++d) {
            const float4 v = src[d];
            unsigned uc0 = __float_as_uint(v.x), uc1 = __float_as_uint(v.y);
            unsigned uc2 = __float_as_uint(v.z), uc3 = __float_as_uint(v.w);
            unsigned hc01 = (uc1 & 0xFFFF0000u) | (uc0 >> 16);
            unsigned hc23 = (uc3 & 0xFFFF0000u) | (uc2 >> 16);
            float lc0 = v.x - __uint_as_float(uc0 & 0xFFFF0000u);
            float lc1 = v.y - __uint_as_float(uc1 & 0xFFFF0000u);
            float lc2 = v.z - __uint_as_float(uc2 & 0xFFFF0000u);
            float lc3 = v.w - __uint_as_float(uc3 & 0xFFFF0000u);
            unsigned lc01 = (__float_as_uint(lc1) & 0xFFFF0000u) | (__float_as_uint(lc0) >> 16);
            unsigned lc23 = (__float_as_uint(lc3) & 0xFFFF0000u) | (__float_as_uint(lc2) >> 16);
            chcl[(tid >> 4) * 64 + d * 16 + (tid & 15)] = (u32x4){hc01, hc23, lc01, lc23};
            ss = fmaf(v.x, v.x, fmaf(v.y, v.y, fmaf(v.z, v.z, fmaf(v.w, v.w, ss))));
        }
        cnorm[tid] = -0.5f * ss;
    }
    __syncthreads();

    const int w   = tid >> 6;     // wave 0..7
    const int l   = tid & 63;
    const int col = l & 15;       // x-row within 16-row sub-tile (MFMA B/C col)
    const int ds  = l >> 4;       // k-segment / C row-group (codes)
    const int n0  = (g << 10) + (w << 7);   // 128 rows per wave

    const float* xp = embeds + (size_t)(n0 + col) * DIMS + m * DSUB + ds * 4;
    const u32x4* av  = chcl + l;                       // + kt*64 per k-tile
    const f32x4* hvp = (const f32x4*)cnorm + ds;       // + kt*4 per k-tile
    const unsigned MSK = 0xFFFFFF00u;
    const size_t RS = 16 * DIMS;                       // 16-row stride

    #pragma unroll 1
    for (int p = 0; p < 4; ++p) {
        const float4 xva = *(const float4*)(xp + (size_t)(2 * p) * RS);
        const float4 xvb = *(const float4*)(xp + (size_t)(2 * p + 1) * RS);
        s16x8 B1a, B2a, B1b, B2b;
        mk_bfrags(xva, B1a, B2a);
        mk_bfrags(xvb, B1b, B2b);

        float b0 = -3e38f, s0 = -3e38f, b1 = -3e38f, s1 = -3e38f;

        #pragma unroll 2
        for (int kt = 0; kt < 16; ++kt) {
            s16x8 A = __builtin_bit_cast(s16x8, av[kt * 64]);  // consecutive b128
            f32x4 h = hvp[kt * 4];                             // broadcast b128
            f32x4 a0 = mfma32(A, B1a, h); a0 = mfma32(A, B2a, a0);
            f32x4 a1 = mfma32(A, B1b, h); a1 = mfma32(A, B2b, a1);

            // Pack code into low-8 mantissa bits; exact top-2 via med3:
            //   s = max(s, med3(q0,q1,b)); b = max(b, max(q0,q1)).
            {
                float q0 = __uint_as_float((__float_as_uint(a0[0]) & MSK) | (unsigned)(kt * 16 + 0));
                float q1 = __uint_as_float((__float_as_uint(a0[1]) & MSK) | (unsigned)(kt * 16 + 1));
                s0 = fmaxf(s0, __builtin_amdgcn_fmed3f(q0, q1, b0));
                b0 = fmaxf(b0, fmaxf(q0, q1));
                float q2 = __uint_as_float((__float_as_uint(a0[2]) & MSK) | (unsigned)(kt * 16 + 2));
                float q3 = __uint_as_float((__float_as_uint(a0[3]) & MSK) | (unsigned)(kt * 16 + 3));
                s0 = fmaxf(s0, __builtin_amdgcn_fmed3f(q2, q3, b0));
                b0 = fmaxf(b0, fmaxf(q2, q3));
            }
            {
                float q0 = __uint_as_float((__float_as_uint(a1[0]) & MSK) | (unsigned)(kt * 16 + 0));
                float q1 = __uint_as_float((__float_as_uint(a1[1]) & MSK) | (unsigned)(kt * 16 + 1));
                s1 = fmaxf(s1, __builtin_amdgcn_fmed3f(q0, q1, b1));
                b1 = fmaxf(b1, fmaxf(q0, q1));
                float q2 = __uint_as_float((__float_as_uint(a1[2]) & MSK) | (unsigned)(kt * 16 + 2));
                float q3 = __uint_as_float((__float_as_uint(a1[3]) & MSK) | (unsigned)(kt * 16 + 3));
                s1 = fmaxf(s1, __builtin_amdgcn_fmed3f(q2, q3, b1));
                b1 = fmaxf(b1, fmaxf(q2, q3));
            }
        }

        // Fold the lane-constant ds*4 into the packed code (low byte <= 243+12).
        const unsigned d4 = (unsigned)(ds * 4);
        b0 = __uint_as_float(__float_as_uint(b0) + d4);
        s0 = __uint_as_float(__float_as_uint(s0) + d4);
        b1 = __uint_as_float(__float_as_uint(b1) + d4);
        s1 = __uint_as_float(__float_as_uint(s1) + d4);

        // Combine the 4 code-partitions (xor 16, 32): all lanes agree on both chains.
        #pragma unroll
        for (int msk = 16; msk <= 32; msk <<= 1) {
            float o;
            o = __shfl_xor(b0, msk); float q0 = __shfl_xor(s0, msk);
            s0 = fmaxf(fmaxf(s0, q0), fminf(b0, o)); b0 = fmaxf(b0, o);
            o = __shfl_xor(b1, msk); float q1 = __shfl_xor(s1, msk);
            s1 = fmaxf(fmaxf(s1, q1), fminf(b1, o)); b1 = fmaxf(b1, o);
        }

        // Lane l (l<32) owns row n0+p*32+l: chain0 = rows 0..15, chain1 = 16..31.
        if (l < 32) {
            float bs_ = (l & 16) ? b1 : b0;
            float ss_ = (l & 16) ? s1 : s0;
            const int row = n0 + p * 32 + l;
            outb[(size_t)row * (DIMS * 4) + m] =
                (unsigned char)(__float_as_uint(bs_) & 255u);

            float gap = __uint_as_float(__float_as_uint(bs_) & MSK) -
                        __uint_as_float(__float_as_uint(ss_) & MSK);
            if (gap < MARGIN) {
                unsigned ent = (unsigned)(row * 64 + m);
                unsigned q = atomicAdd(&fl_cnt, 1u);
                if (q < FLCAP) fl_buf[q] = ent;
                else { unsigned qq = atomicAdd(flag_cnt, 1u);
                       if (qq < flag_cap) flag_list[qq] = ent; }
            }
        }
    }

    // ---- One global atomic per block; coalesced flag flush ----
    __syncthreads();
    unsigned c = fl_cnt; if (c > FLCAP) c = FLCAP;
    if (tid == 0) fl_base = atomicAdd(flag_cnt, c);
    __syncthreads();
    const unsigned base = fl_base;
    for (unsigned i = tid; i < c; i += 512) {
        unsigned q = base + i;
        if (q < flag_cap) flag_list[q] = fl_buf[i];
    }
}

// One wave per flagged (n,m): exact f64 distances, first-min tie-break; fix the byte.
__global__ __launch_bounds__(256) void pq_refine(
    const float* __restrict__ embeds,
    const float* __restrict__ codebooks,
    unsigned char* __restrict__ outb,
    const unsigned* __restrict__ flag_cnt,
    const unsigned* __restrict__ flag_list,
    unsigned flag_cap)
{
    unsigned cnt = *flag_cnt;
    if (cnt > flag_cap) cnt = flag_cap;
    const int l = threadIdx.x & 63;
    const unsigned wid = (blockIdx.x << 2) | (unsigned)(threadIdx.x >> 6);
    const unsigned nw  = gridDim.x << 2;

    for (unsigned i = wid; i < cnt; i += nw) {
        const unsigned e = flag_list[i];
        const int n = (int)(e >> 6), m = (int)(e & 63u);
        const float* xrow = embeds + (size_t)n * DIMS + m * DSUB;
        double xd[DSUB];
        #pragma unroll
        for (int dd = 0; dd < DSUB; ++dd) xd[dd] = (double)xrow[dd];
        const float* cbm = codebooks + (size_t)m * (KCODE * DSUB);

        double bd = 1e300;
        int bi = 0;
        #pragma unroll 1
        for (int cc = 0; cc < 4; ++cc) {
            const int c = l * 4 + cc;                 // lane-local ascending
            const float* cp = cbm + c * DSUB;
            double s = 0.0;
            #pragma unroll
            for (int dd = 0; dd < DSUB; ++dd) {
                double diff = xd[dd] - (double)cp[dd];
                s = fma(diff, diff, s);
            }
            if (s < bd) { bd = s; bi = c; }
        }
        #pragma unroll
        for (int msk = 1; msk <= 32; msk <<= 1) {
            double ob = __shfl_xor(bd, msk);
            int   oi  = __shfl_xor(bi, msk);
            if (ob < bd || (ob == bd && oi < bi)) { bd = ob; bi = oi; }
        }
        if (l == 0) outb[(size_t)n * (DIMS * 4) + m] = (unsigned char)bi;
    }
}

// Phase 3: code bytes -> full output rows, perfectly coalesced 4KB stores.
// Thread tid: subspace m = tid>>2, segment seg = tid&3. 8 rows per block.
// Each block reads only bytes of rows it overwrites itself (sync inside).
__global__ __launch_bounds__(256) void pq_gather(
    const float* __restrict__ codebooks,
    float* __restrict__ out)
{
    const unsigned char* outb = (const unsigned char*)out;
    const int tid = threadIdx.x;
    const int m   = tid >> 2;
    const int seg = tid & 3;
    const int n0  = blockIdx.x * 8;

    unsigned char ids[8];
    #pragma unroll
    for (int r = 0; r < 8; ++r)
        ids[r] = outb[(size_t)(n0 + r) * (DIMS * 4) + m];
    __syncthreads();   // all idx reads done before any thread overwrites row bytes

    #pragma unroll
    for (int r = 0; r < 8; ++r) {
        const float4 v = *(const float4*)(codebooks +
                          ((size_t)m * KCODE + ids[r]) * DSUB + seg * 4);
        *(float4*)(out + (size_t)(n0 + r) * DIMS + tid * 4) = v;
    }
}

extern "C" void kernel_launch(void* const* d_in, const int* in_sizes, int n_in,
                              void* d_out, int out_size, void* d_ws, size_t ws_size,
                              hipStream_t stream)
{
    const float* embeds    = (const float*)d_in[0];
    const float* codebooks = (const float*)d_in[1];
    float* out = (float*)d_out;

    unsigned* flag_cnt  = (unsigned*)d_ws;
    unsigned* flag_list = (unsigned*)d_ws + 4;   // 16B offset
    unsigned flag_cap = 0;
    if (ws_size >= 32) {
        size_t cap = (ws_size - 16) / sizeof(unsigned);
        flag_cap = (cap > 0x7FFFFFFFull) ? 0x7FFFFFFFu : (unsigned)cap;
    }

    hipMemsetAsync(d_ws, 0, 16, stream);

    pq_main<<<dim3(1024), dim3(512), 0, stream>>>(
        embeds, codebooks, (unsigned char*)d_out, flag_cnt, flag_list, flag_cap);

    pq_refine<<<dim3(256), dim3(256), 0, stream>>>(
        embeds, codebooks, (unsigned char*)d_out, flag_cnt, flag_list, flag_cap);

    pq_gather<<<dim3(2048), dim3(256), 0, stream>>>(codebooks, out);
}